// Round 2
// baseline (14022.063 us; speedup 1.0000x reference)
//
#include <hip/hip_runtime.h>

#define NODES    16384
#define EDGES    262144
#define OUT_CH   304      // 64 + 32*3 + 16*9
#define EB       16       // edges per block
#define NTHREADS 256

// out[e] += sum_b ( sum_l rad[l]*P[c,l,b] ) * feat[e][b]      (scalar feature)
template<int B, int NE>
__device__ __forceinline__ void contract_s(const float* __restrict__ Pp,
    const float (*rad_r)[8], const float* const* feat, float* racc)
{
    for (int b0 = 0; b0 < B; b0 += 4) {
        float4 p[8];
        #pragma unroll
        for (int l = 0; l < 8; ++l)
            p[l] = *reinterpret_cast<const float4*>(Pp + l*B + b0);
        #pragma unroll
        for (int e = 0; e < NE; ++e) {
            float t0 = 0.f, t1 = 0.f, t2 = 0.f, t3 = 0.f;
            #pragma unroll
            for (int l = 0; l < 8; ++l) {
                float r = rad_r[e][l];
                t0 = fmaf(r, p[l].x, t0);
                t1 = fmaf(r, p[l].y, t1);
                t2 = fmaf(r, p[l].z, t2);
                t3 = fmaf(r, p[l].w, t3);
            }
            const float* f = feat[e] + b0;
            racc[e] = fmaf(t0, f[0], racc[e]);
            racc[e] = fmaf(t1, f[1], racc[e]);
            racc[e] = fmaf(t2, f[2], racc[e]);
            racc[e] = fmaf(t3, f[3], racc[e]);
        }
    }
}

// vector (3-component) feature, feat layout [b][3]
template<int B, int NE>
__device__ __forceinline__ void contract_v3(const float* __restrict__ Pp,
    const float (*rad_r)[8], const float* const* feat, float (*racc)[3])
{
    for (int b0 = 0; b0 < B; b0 += 4) {
        float4 p[8];
        #pragma unroll
        for (int l = 0; l < 8; ++l)
            p[l] = *reinterpret_cast<const float4*>(Pp + l*B + b0);
        #pragma unroll
        for (int e = 0; e < NE; ++e) {
            float tv[4] = {0.f, 0.f, 0.f, 0.f};
            #pragma unroll
            for (int l = 0; l < 8; ++l) {
                float r = rad_r[e][l];
                tv[0] = fmaf(r, p[l].x, tv[0]);
                tv[1] = fmaf(r, p[l].y, tv[1]);
                tv[2] = fmaf(r, p[l].z, tv[2]);
                tv[3] = fmaf(r, p[l].w, tv[3]);
            }
            #pragma unroll
            for (int bb = 0; bb < 4; ++bb) {
                const float* f = feat[e] + (b0+bb)*3;
                racc[e][0] = fmaf(tv[bb], f[0], racc[e][0]);
                racc[e][1] = fmaf(tv[bb], f[1], racc[e][1]);
                racc[e][2] = fmaf(tv[bb], f[2], racc[e][2]);
            }
        }
    }
}

// 9-component feature, feat layout [b][9]
template<int B, int NE>
__device__ __forceinline__ void contract_v9(const float* __restrict__ Pp,
    const float (*rad_r)[8], const float* const* feat, float (*racc)[9])
{
    for (int b0 = 0; b0 < B; b0 += 4) {
        float4 p[8];
        #pragma unroll
        for (int l = 0; l < 8; ++l)
            p[l] = *reinterpret_cast<const float4*>(Pp + l*B + b0);
        #pragma unroll
        for (int e = 0; e < NE; ++e) {
            float tv[4] = {0.f, 0.f, 0.f, 0.f};
            #pragma unroll
            for (int l = 0; l < 8; ++l) {
                float r = rad_r[e][l];
                tv[0] = fmaf(r, p[l].x, tv[0]);
                tv[1] = fmaf(r, p[l].y, tv[1]);
                tv[2] = fmaf(r, p[l].z, tv[2]);
                tv[3] = fmaf(r, p[l].w, tv[3]);
            }
            #pragma unroll
            for (int bb = 0; bb < 4; ++bb) {
                const float* f = feat[e] + (b0+bb)*9;
                #pragma unroll
                for (int k = 0; k < 9; ++k)
                    racc[e][k] = fmaf(tv[bb], f[k], racc[e][k]);
            }
        }
    }
}

__global__ __launch_bounds__(NTHREADS, 2) void edge_kernel(
    const float* __restrict__ xa_g, const float* __restrict__ xv_g, const float* __restrict__ xd_g,
    const float* __restrict__ rij_g,
    const float* __restrict__ P000, const float* __restrict__ P110, const float* __restrict__ P220,
    const float* __restrict__ P011, const float* __restrict__ P101, const float* __restrict__ P121,
    const float* __restrict__ P211, const float* __restrict__ P111,
    const float* __restrict__ P022, const float* __restrict__ P112, const float* __restrict__ P202,
    const float* __restrict__ P222, const float* __restrict__ P212,
    const int* __restrict__ src, const int* __restrict__ dst,
    float* __restrict__ out)
{
    __shared__ float s_rad[EB][8];
    __shared__ float s_rh[EB][4];
    __shared__ float s_xa[EB][64];
    __shared__ float s_sv[EB][32];
    __shared__ float s_sd[EB][16];
    __shared__ float s_xv[EB][32][3];
    __shared__ float s_uv[EB][16][3];
    __shared__ float s_wd[EB][16][3];
    __shared__ float s_cr[EB][32][3];
    __shared__ float s_xd[EB][16][9];
    __shared__ float s_m[EB][OUT_CH];
    __shared__ int   s_dst[EB];
    __shared__ int   s_srcn[EB];

    const int t  = threadIdx.x;
    const int e0 = blockIdx.x * EB;

    // ---- phase 1a: per-edge radial basis + rh (16 lanes) ----
    if (t < EB) {
        const int e = e0 + t;
        float r0 = rij_g[e*3+0];
        float r1 = rij_g[e*3+1];
        float r2 = rij_g[e*3+2];
        float x_sq = (r0*r0 + r1*r1 + r2*r2) * 0.125f;   // /R0, R0=8
        float q  = sqrtf(x_sq);
        float w  = fmaxf(1.0f - x_sq, 0.0f);
        const float PI = 3.14159265358979323846f;
        #pragma unroll
        for (int n = 0; n < 8; ++n)
            s_rad[t][n] = cosf(PI * (float)n * q) * w;
        float y0 = r0*0.875f, y1 = r1*0.875f, y2 = r2*0.875f;  // * 7/R0
        float nn = sqrtf(y0*y0 + y1*y1 + y2*y2);
        float sc = tanhf(nn) / fmaxf(nn, 1e-6f);
        s_rh[t][0] = y0*sc; s_rh[t][1] = y1*sc; s_rh[t][2] = y2*sc; s_rh[t][3] = 0.f;
        s_dst[t]  = dst[e];
        s_srcn[t] = src[e];
    }
    // zero message accumulators
    for (int idx = t; idx < EB*OUT_CH; idx += NTHREADS)
        (&s_m[0][0])[idx] = 0.0f;
    __syncthreads();

    // ---- phase 1b: gather node features, derived per-edge features ----
    {
        const int el  = t >> 4;
        const int sub = t & 15;
        const int n   = s_srcn[el];
        const float rh0 = s_rh[el][0], rh1 = s_rh[el][1], rh2 = s_rh[el][2];
        #pragma unroll
        for (int k = 0; k < 4; ++k) {
            int b = sub + 16*k;
            s_xa[el][b] = xa_g[n*64 + b];
        }
        #pragma unroll
        for (int k = 0; k < 2; ++k) {
            int b = sub + 16*k;
            float v0 = xv_g[(n*32 + b)*3 + 0];
            float v1 = xv_g[(n*32 + b)*3 + 1];
            float v2 = xv_g[(n*32 + b)*3 + 2];
            s_xv[el][b][0] = v0; s_xv[el][b][1] = v1; s_xv[el][b][2] = v2;
            s_sv[el][b] = rh0*v0 + rh1*v1 + rh2*v2;
            s_cr[el][b][0] = rh1*v2 - rh2*v1;
            s_cr[el][b][1] = rh2*v0 - rh0*v2;
            s_cr[el][b][2] = rh0*v1 - rh1*v0;
        }
        {
            int b = sub;
            float d[9];
            #pragma unroll
            for (int k = 0; k < 9; ++k) {
                d[k] = xd_g[(n*16 + b)*9 + k];
                s_xd[el][b][k] = d[k];
            }
            float uv0 = d[0]*rh0 + d[1]*rh1 + d[2]*rh2;
            float uv1 = d[3]*rh0 + d[4]*rh1 + d[5]*rh2;
            float uv2 = d[6]*rh0 + d[7]*rh1 + d[8]*rh2;
            s_uv[el][b][0] = uv0; s_uv[el][b][1] = uv1; s_uv[el][b][2] = uv2;
            s_wd[el][b][0] = rh0*d[0] + rh1*d[3] + rh2*d[6];
            s_wd[el][b][1] = rh0*d[1] + rh1*d[4] + rh2*d[7];
            s_wd[el][b][2] = rh0*d[2] + rh1*d[5] + rh2*d[8];
            s_sd[el][b] = rh0*uv0 + rh1*uv1 + rh2*uv2;
        }
    }
    __syncthreads();

    // ---- pass A: m_a (c in [0,64), 4 edge-groups x 4 edges) ----
    {
        const int c  = t & 63;
        const int eg = t >> 6;
        const int el0 = eg*4;
        float rad_r[4][8];
        #pragma unroll
        for (int e4 = 0; e4 < 4; ++e4)
            #pragma unroll
            for (int l = 0; l < 8; ++l) rad_r[e4][l] = s_rad[el0+e4][l];
        float racc[4] = {0,0,0,0};
        const float* f[4];
        f[0]=&s_xa[el0][0]; f[1]=&s_xa[el0+1][0]; f[2]=&s_xa[el0+2][0]; f[3]=&s_xa[el0+3][0];
        contract_s<64,4>(P000 + c*(8*64), rad_r, f, racc);
        f[0]=&s_sv[el0][0]; f[1]=&s_sv[el0+1][0]; f[2]=&s_sv[el0+2][0]; f[3]=&s_sv[el0+3][0];
        contract_s<32,4>(P110 + c*(8*32), rad_r, f, racc);
        f[0]=&s_sd[el0][0]; f[1]=&s_sd[el0+1][0]; f[2]=&s_sd[el0+2][0]; f[3]=&s_sd[el0+3][0];
        contract_s<16,4>(P220 + c*(8*16), rad_r, f, racc);
        #pragma unroll
        for (int e4 = 0; e4 < 4; ++e4)
            s_m[el0+e4][c] += racc[e4];
    }

    // ---- pass V: m_v (c in [0,32), 8 edge-groups x 2 edges) ----
    {
        const int c  = t & 31;
        const int eg = t >> 5;
        const int el0 = eg*2;
        float rad_r[2][8];
        #pragma unroll
        for (int e2 = 0; e2 < 2; ++e2)
            #pragma unroll
            for (int l = 0; l < 8; ++l) rad_r[e2][l] = s_rad[el0+e2][l];
        float accv[2][3] = {{0,0,0},{0,0,0}};
        float accs[2] = {0,0};
        const float* fv[2]; const float* fs[2];
        fv[0]=&s_xv[el0][0][0]; fv[1]=&s_xv[el0+1][0][0];
        contract_v3<32,2>(P011 + c*(8*32), rad_r, fv, accv);
        fv[0]=&s_uv[el0][0][0]; fv[1]=&s_uv[el0+1][0][0];
        contract_v3<16,2>(P121 + c*(8*16), rad_r, fv, accv);
        fv[0]=&s_cr[el0][0][0]; fv[1]=&s_cr[el0+1][0][0];
        contract_v3<32,2>(P111 + c*(8*32), rad_r, fv, accv);
        fs[0]=&s_xa[el0][0]; fs[1]=&s_xa[el0+1][0];
        contract_s<64,2>(P101 + c*(8*64), rad_r, fs, accs);
        fs[0]=&s_sv[el0][0]; fs[1]=&s_sv[el0+1][0];
        contract_s<32,2>(P211 + c*(8*32), rad_r, fs, accs);
        #pragma unroll
        for (int e2 = 0; e2 < 2; ++e2) {
            const int el = el0 + e2;
            #pragma unroll
            for (int i = 0; i < 3; ++i)
                s_m[el][64 + c*3 + i] += accv[e2][i] + s_rh[el][i]*accs[e2];
        }
    }

    // ---- pass D: m_d (c in [0,16), 16 edge-groups x 1 edge) ----
    {
        const int c  = t & 15;
        const int el = t >> 4;
        float rad_r[1][8];
        #pragma unroll
        for (int l = 0; l < 8; ++l) rad_r[0][l] = s_rad[el][l];
        float accd[1][9] = {{0,0,0,0,0,0,0,0,0}};
        float accj[1][3] = {{0,0,0}};
        float acc0[1] = {0};
        const float* f1[1];
        f1[0] = &s_xd[el][0][0];
        contract_v9<16,1>(P022 + c*(8*16), rad_r, f1, accd);
        f1[0] = &s_xv[el][0][0];
        contract_v3<32,1>(P112 + c*(8*32), rad_r, f1, accj);
        f1[0] = &s_wd[el][0][0];
        contract_v3<16,1>(P222 + c*(8*16), rad_r, f1, accj);
        f1[0] = &s_cr[el][0][0];
        contract_v3<32,1>(P212 + c*(8*32), rad_r, f1, accj);
        f1[0] = &s_xa[el][0];
        contract_s<64,1>(P202 + c*(8*64), rad_r, f1, acc0);
        const float rhv[3] = { s_rh[el][0], s_rh[el][1], s_rh[el][2] };
        #pragma unroll
        for (int i = 0; i < 3; ++i)
            #pragma unroll
            for (int j = 0; j < 3; ++j)
                s_m[el][160 + c*9 + i*3 + j] +=
                    accd[0][i*3+j] + rhv[i]*(accj[0][j] + rhv[j]*acc0[0]);
    }
    __syncthreads();

    // ---- scatter: atomicAdd into f32 output ----
    for (int idx = t; idx < EB*OUT_CH; idx += NTHREADS) {
        int el = idx / OUT_CH;
        int ch = idx - el*OUT_CH;
        atomicAdd(&out[(size_t)s_dst[el]*OUT_CH + ch], s_m[el][ch]);
    }
}

extern "C" void kernel_launch(void* const* d_in, const int* in_sizes, int n_in,
                              void* d_out, int out_size, void* d_ws, size_t ws_size,
                              hipStream_t stream)
{
    const float* xa  = (const float*)d_in[0];
    const float* xv  = (const float*)d_in[1];
    const float* xd  = (const float*)d_in[2];
    const float* rij = (const float*)d_in[3];
    const float* P000 = (const float*)d_in[4];
    const float* P110 = (const float*)d_in[5];
    const float* P220 = (const float*)d_in[6];
    const float* P011 = (const float*)d_in[7];
    const float* P101 = (const float*)d_in[8];
    const float* P121 = (const float*)d_in[9];
    const float* P211 = (const float*)d_in[10];
    const float* P111 = (const float*)d_in[11];
    const float* P022 = (const float*)d_in[12];
    const float* P112 = (const float*)d_in[13];
    const float* P202 = (const float*)d_in[14];
    const float* P222 = (const float*)d_in[15];
    const float* P212 = (const float*)d_in[16];
    const int* src = (const int*)d_in[17];
    const int* dst = (const int*)d_in[18];

    float* out = (float*)d_out;

    // harness re-poisons d_out to 0xAA before every timed launch -> zero it ourselves
    hipMemsetAsync(d_out, 0, (size_t)out_size * sizeof(float), stream);

    edge_kernel<<<EDGES/EB, NTHREADS, 0, stream>>>(
        xa, xv, xd, rij,
        P000, P110, P220, P011, P101, P121, P211, P111,
        P022, P112, P202, P222, P212,
        src, dst, out);
}